// Round 12
// baseline (492.298 us; speedup 1.0000x reference)
//
#include <hip/hip_runtime.h>

// ResidualBlock2 (AdderNet): two adder-convs + BN + ReLU + residual.
// N=32, C=32, H=W=32, K=3. No multiplies -> no MFMA; pure VALU
// (2 instr per |x-w|; VALU floor 7.7us/conv).
// R12: R11's ci-split compute core (validated ~10-11us) + staging latency
// fix: float4 x-staging (1 f4 task/thread/half vs 6-7 scalar loads) and
// T14 async split-half (issue half-B global loads -> compute half-A ->
// ds_write B -> barrier -> compute B): half-B HBM latency hides under
// compute-A. BN folds distributed over all threads.

#define QSCALE (2.5f / 127.f)

__device__ __forceinline__ float quantf(float w) {
  float v = rintf(w * (1.0f / QSCALE));     // round-half-even = jnp.round
  v = fminf(fmaxf(v, -127.f), 127.f);
  return v * QSCALE;
}

// quantize + pack: WQ[(ci*9+tap)*32 + co] = quant(w[co][ci*9+tap])
__global__ __launch_bounds__(256) void quant_k(const float* __restrict__ w1,
                                               const float* __restrict__ w2,
                                               float* __restrict__ q1,
                                               float* __restrict__ q2) {
  int i = blockIdx.x * 256 + threadIdx.x;
  if (i >= 18432) return;
  const float* w = (i < 9216) ? w1 : w2;
  float* dst = (i < 9216) ? q1 : q2;
  int j = (i < 9216) ? i : i - 9216;
  int co = j / 288;
  int r = j - co * 288;                     // r = ci*9 + tap
  dst[r * 32 + co] = quantf(w[j]);
}

// Grid 256 = 32 n x 8 rowgroups(4 rows). Block 1024 thr = 16 waves.
// wave: oct = wv&3 (co oct*8..+7), slice = wv>>2; wave computes
// ci in {slice+4j} (half A: j<4 -> ci<16; half B: j>=4).
// lane l: quad = l>>5 (co sub-quad), p = l&31: row = p>>3, g = p&7
// (cols 4g..4g+3). acc[4 cols][4 co] = 16/lane. 16 waves/CU = 4/SIMD.
// Partials ps/pq: chunk-major [256][32], chunk = n*8+rg (coalesced).
template <bool AFFINE>
__global__ __launch_bounds__(1024, 4) void conv_k(
    const float* __restrict__ in,       // [32][32][32][32] conv input
    const float* __restrict__ wq,       // packed [288][32] this conv
    const float* __restrict__ ps_prev,  // [256][32] prev partial sums (or null)
    const float* __restrict__ pq_prev,  // [256][32] prev partial sumsq
    const float* __restrict__ wq_prev,  // packed prev weights (for wb)
    const float* __restrict__ gprev,    // prev gamma
    const float* __restrict__ bprev,    // prev beta
    float* __restrict__ outb,           // raw conv out
    float* __restrict__ ps_out,         // [256][32]
    float* __restrict__ pq_out) {
  // xs = smem[0..6912) : [32 ci][6 rows][36 cols] (idx c <-> global col c-1)
  // wls = smem[6912..16128) : flat [288][32]
  // red aliases smem[0..12288) after compute (SoA [48][256])
  __shared__ __align__(16) float smem[16128];      // 64512 B
  __shared__ float r2a[32][32], r2b[32][32], r2c[32][32];
  __shared__ float abuf[32], bbuf[32];

  float* xs = smem;
  float* wls = smem + 6912;

  const int tid = threadIdx.x;
  const int blk = blockIdx.x;
  const int n = blk >> 3, rg = blk & 7;
  const int h0 = rg << 2;

  if (AFFINE) {
    // Redundant per-block BN1 fold, distributed over all 1024 threads.
    const int c = tid & 31, ch = tid >> 5;    // ch 0..31
    float s = 0.f, q = 0.f;
    #pragma unroll
    for (int k = 0; k < 8; ++k) {
      s += ps_prev[(ch * 8 + k) * 32 + c];
      q += pq_prev[(ch * 8 + k) * 32 + c];
    }
    float wbp = 0.f;
    #pragma unroll
    for (int uu = 0; uu < 9; ++uu)
      wbp += fabsf(wq_prev[(ch * 9 + uu) * 32 + c]);
    r2a[c][ch] = s; r2b[c][ch] = q; r2c[c][ch] = wbp;
    __syncthreads();
    if (tid < 32) {
      double S = 0.0, Q = 0.0; float W = 0.f;
      #pragma unroll 8
      for (int k = 0; k < 32; ++k) {
        S += (double)r2a[tid][k]; Q += (double)r2b[tid][k]; W += r2c[tid][k];
      }
      const double M = 32768.0;
      const double mu = S / M;
      const double var = Q / M - mu * mu;
      const double inv = 1.0 / sqrt(var + 1e-5);
      const double g = (double)gprev[tid];
      abuf[tid] = (float)(g * inv);
      bbuf[tid] = (float)((double)bprev[tid] + (double)(W * (1.f / 288.f)) - g * inv * mu);
    }
    __syncthreads();
  }

  // ---- stage weights (flat float4, coalesced) + x half A (ci 0..15)
  {
    const float4* src = (const float4*)wq;
    float4* dst = (float4*)wls;
    for (int i = tid; i < 2304; i += 1024) dst[i] = src[i];
  }
  // x task decode (864 tasks/half): ci_h = t/54, tr = (t%54)/9, k = t%9.
  // k<8: f4 load global cols 4k..4k+3 -> xs idx 4k+1..4k+4; k==8: zeros.
  if (tid < 864) {
    const int ci = tid / 54;
    const int rem = tid - ci * 54;
    const int tr = rem / 9, k = rem - tr * 9;
    const int h = h0 - 1 + tr;
    float* dst = xs + ci * 216 + tr * 36;
    if (k < 8) {
      float4 v = {0.f, 0.f, 0.f, 0.f};
      if ((unsigned)h < 32u) {
        v = *(const float4*)(in + (((n * 32 + ci) * 32 + h) * 32 + 4 * k));
        if (AFFINE) {
          const float av = abuf[ci], bv = bbuf[ci];
          v.x = fmaxf(fmaf(av, v.x, bv), 0.f);
          v.y = fmaxf(fmaf(av, v.y, bv), 0.f);
          v.z = fmaxf(fmaf(av, v.z, bv), 0.f);
          v.w = fmaxf(fmaf(av, v.w, bv), 0.f);
        }
      }
      dst[4 * k + 1] = v.x; dst[4 * k + 2] = v.y;
      dst[4 * k + 3] = v.z; dst[4 * k + 4] = v.w;
    } else {
      dst[0] = 0.f; dst[33] = 0.f; dst[34] = 0.f; dst[35] = 0.f;
    }
  }
  __syncthreads();

  const int wv = tid >> 6;
  const int oct = wv & 3, slice = wv >> 2;
  const int l = tid & 63;
  const int quad = l >> 5, p = l & 31;
  const int row = p >> 3, g = p & 7;

  float acc[4][4];
  #pragma unroll
  for (int j = 0; j < 4; ++j)
    #pragma unroll
    for (int k = 0; k < 4; ++k) acc[j][k] = 0.f;

  const float* xpb = xs + row * 36 + 4 * g;
  const float* wpb = wls + oct * 8 + quad * 4;

  auto comp = [&](int ci) {
    const float* xp = xpb + ci * 216;
    float xw[3][6];
    #pragma unroll
    for (int kh = 0; kh < 3; ++kh) {
      const float4 A = *(const float4*)(xp + kh * 36);
      const float2 B = *(const float2*)(xp + kh * 36 + 4);
      xw[kh][0] = A.x; xw[kh][1] = A.y; xw[kh][2] = A.z; xw[kh][3] = A.w;
      xw[kh][4] = B.x; xw[kh][5] = B.y;
    }
    const float* wp = wpb + ci * 288;
    #pragma unroll
    for (int t = 0; t < 9; ++t) {
      const float4 W = *(const float4*)(wp + t * 32);
      const int kh = t / 3, kw = t - kh * 3;
      #pragma unroll
      for (int j = 0; j < 4; ++j) {
        const float xv = xw[kh][j + kw];
        acc[j][0] += fabsf(xv - W.x);
        acc[j][1] += fabsf(xv - W.y);
        acc[j][2] += fabsf(xv - W.z);
        acc[j][3] += fabsf(xv - W.w);
      }
    }
  };

  // ---- issue half-B global loads (fly under compute A)
  float4 bv = {0.f, 0.f, 0.f, 0.f};
  int bci = 0, btr = 0, bk = 0;
  const bool bact = tid < 864;
  if (bact) {
    bci = 16 + tid / 54;
    const int rem = tid - (bci - 16) * 54;
    btr = rem / 9; bk = rem - btr * 9;
    const int h = h0 - 1 + btr;
    if (bk < 8 && (unsigned)h < 32u)
      bv = *(const float4*)(in + (((n * 32 + bci) * 32 + h) * 32 + 4 * bk));
  }

  // ---- compute half A
  comp(slice); comp(slice + 4); comp(slice + 8); comp(slice + 12);

  // ---- write half B to LDS
  if (bact) {
    float* dst = xs + bci * 216 + btr * 36;
    if (bk < 8) {
      const int h = h0 - 1 + btr;
      if (AFFINE && (unsigned)h < 32u) {
        const float av = abuf[bci], bvv = bbuf[bci];
        bv.x = fmaxf(fmaf(av, bv.x, bvv), 0.f);
        bv.y = fmaxf(fmaf(av, bv.y, bvv), 0.f);
        bv.z = fmaxf(fmaf(av, bv.z, bvv), 0.f);
        bv.w = fmaxf(fmaf(av, bv.w, bvv), 0.f);
      }
      dst[4 * bk + 1] = bv.x; dst[4 * bk + 2] = bv.y;
      dst[4 * bk + 3] = bv.z; dst[4 * bk + 4] = bv.w;
    } else {
      dst[0] = 0.f; dst[33] = 0.f; dst[34] = 0.f; dst[35] = 0.f;
    }
  }
  __syncthreads();

  // ---- compute half B
  comp(slice + 16); comp(slice + 20); comp(slice + 24); comp(slice + 28);
  __syncthreads();   // xs/wls reads done; red may overwrite

  // ---- cross-slice reduce, SoA: red[(s*16 + j*4+k)*256 + oct*64 + l]
  float* red = smem;
  const int lane16 = oct * 64 + l;
  if (slice != 0) {
    const int sb = (slice - 1) * 16;
    #pragma unroll
    for (int j = 0; j < 4; ++j)
      #pragma unroll
      for (int k = 0; k < 4; ++k)
        red[(sb + j * 4 + k) * 256 + lane16] = acc[j][k];
  }
  __syncthreads();

  if (slice == 0) {
    #pragma unroll
    for (int s = 0; s < 3; ++s)
      #pragma unroll
      for (int j = 0; j < 4; ++j)
        #pragma unroll
        for (int k = 0; k < 4; ++k)
          acc[j][k] += red[(s * 16 + j * 4 + k) * 256 + lane16];

    const int h = h0 + row;
    float sv[4], qv[4];
    #pragma unroll
    for (int k = 0; k < 4; ++k) {
      const int co = oct * 8 + quad * 4 + k;
      float4 st;
      st.x = -acc[0][k]; st.y = -acc[1][k]; st.z = -acc[2][k]; st.w = -acc[3][k];
      *(float4*)&outb[((n * 32 + co) * 32 + h) * 32 + 4 * g] = st;
      sv[k] = st.x + st.y + st.z + st.w;
      qv[k] = st.x*st.x + st.y*st.y + st.z*st.z + st.w*st.w;
    }
    #pragma unroll
    for (int d = 1; d < 32; d <<= 1) {
      #pragma unroll
      for (int k = 0; k < 4; ++k) {
        sv[k] += __shfl_xor(sv[k], d);
        qv[k] += __shfl_xor(qv[k], d);
      }
    }
    if (p == 0) {   // lane 0 (quad 0) and lane 32 (quad 1): adjacent float4s
      const int chunk = n * 8 + rg;
      float4 s4; s4.x = sv[0]; s4.y = sv[1]; s4.z = sv[2]; s4.w = sv[3];
      float4 q4; q4.x = qv[0]; q4.y = qv[1]; q4.z = qv[2]; q4.w = qv[3];
      ((float4*)(ps_out + chunk * 32))[oct * 2 + quad] = s4;
      ((float4*)(pq_out + chunk * 32))[oct * 2 + quad] = q4;
    }
  }
}

// ---- K4: redundant BN2 fold + relu(a2*o2 + b2 + x). 512 thr, 512 blocks.
__global__ __launch_bounds__(512) void final_k(
    const float* __restrict__ o2, const float* __restrict__ xres,
    const float* __restrict__ ps, const float* __restrict__ pq,
    const float* __restrict__ wq2, const float* __restrict__ g2,
    const float* __restrict__ b2, float* __restrict__ out) {
  __shared__ float r2a[32][16], r2b[32][16], r2c[32][16];
  __shared__ float abuf[32], bbuf[32];
  const int tid = threadIdx.x;
  const int c = tid & 31, ch = tid >> 5;    // ch 0..15
  float s = 0.f, q = 0.f;
  #pragma unroll
  for (int k = 0; k < 16; ++k) {
    s += ps[(ch * 16 + k) * 32 + c];
    q += pq[(ch * 16 + k) * 32 + c];
  }
  float wbp = 0.f;
  #pragma unroll
  for (int uu = 0; uu < 18; ++uu)
    wbp += fabsf(wq2[(ch * 18 + uu) * 32 + c]);
  r2a[c][ch] = s; r2b[c][ch] = q; r2c[c][ch] = wbp;
  __syncthreads();
  if (tid < 32) {
    double S = 0.0, Q = 0.0; float W = 0.f;
    #pragma unroll
    for (int k = 0; k < 16; ++k) {
      S += (double)r2a[tid][k]; Q += (double)r2b[tid][k]; W += r2c[tid][k];
    }
    const double M = 32768.0;
    const double mu = S / M;
    const double var = Q / M - mu * mu;
    const double inv = 1.0 / sqrt(var + 1e-5);
    const double g = (double)g2[tid];
    abuf[tid] = (float)(g * inv);
    bbuf[tid] = (float)((double)b2[tid] + (double)(W * (1.f / 288.f)) - g * inv * mu);
  }
  __syncthreads();

  const int f4 = blockIdx.x * 512 + tid;   // 512 x 512 = 262144 float4s
  const int cc = (f4 >> 8) & 31;
  const float4 o = ((const float4*)o2)[f4];
  const float4 xr = ((const float4*)xres)[f4];
  const float av = abuf[cc], bvv = bbuf[cc];
  float4 r;
  r.x = fmaxf(fmaf(av, o.x, bvv) + xr.x, 0.f);
  r.y = fmaxf(fmaf(av, o.y, bvv) + xr.y, 0.f);
  r.z = fmaxf(fmaf(av, o.z, bvv) + xr.z, 0.f);
  r.w = fmaxf(fmaf(av, o.w, bvv) + xr.w, 0.f);
  ((float4*)out)[f4] = r;
}

extern "C" void kernel_launch(void* const* d_in, const int* in_sizes, int n_in,
                              void* d_out, int out_size, void* d_ws, size_t ws_size,
                              hipStream_t stream) {
  const float* x   = (const float*)d_in[0];
  const float* w1  = (const float*)d_in[1];
  const float* g1  = (const float*)d_in[2];
  const float* be1 = (const float*)d_in[3];
  const float* w2  = (const float*)d_in[4];
  const float* g2  = (const float*)d_in[5];
  const float* be2 = (const float*)d_in[6];
  float* ws = (float*)d_ws;

  float* WQ1 = ws;                  // 9216  (packed [288][32])
  float* WQ2 = ws + 9216;           // 9216
  float* PS1 = ws + 18432;          // [256][32] = 8192
  float* PQ1 = ws + 26624;          // 8192
  float* PS2 = ws + 34816;          // 8192
  float* PQ2 = ws + 43008;          // 8192
  float* O1  = ws + 51200;          // 1048576 (16B aligned)
  float* O2  = O1 + 1048576;        // 1048576
  float* out = (float*)d_out;

  quant_k<<<72, 256, 0, stream>>>(w1, w2, WQ1, WQ2);
  conv_k<false><<<256, 1024, 0, stream>>>(x, WQ1, nullptr, nullptr, nullptr,
                                          nullptr, nullptr, O1, PS1, PQ1);
  conv_k<true><<<256, 1024, 0, stream>>>(O1, WQ2, PS1, PQ1, WQ1, g1, be1,
                                         O2, PS2, PQ2);
  final_k<<<512, 512, 0, stream>>>(O2, x, PS2, PQ2, WQ2, g2, be2, out);
}

// Round 13
// 60.064 us; speedup vs baseline: 8.1963x; 8.1963x over previous
//
#include <hip/hip_runtime.h>

// ResidualBlock2 (AdderNet): two adder-convs + BN + ReLU + residual.
// N=32, C=32, H=W=32, K=3. No multiplies -> no MFMA; pure VALU
// (2 instr per |x-w|; VALU floor 7.7us/conv).
// R13: R11 compute core (validated) + spill-safe parts of R12 only:
// float4 x-staging (synchronous, <=2 rounds/thread; R11 did 6-7 scalar
// rounds), distributed BN fold, 512-thr final_k. R12's async reg-held
// staging caused 487MB/dispatch scratch spill (VGPR 64, rule #20) - reverted.

#define QSCALE (2.5f / 127.f)

__device__ __forceinline__ float quantf(float w) {
  float v = rintf(w * (1.0f / QSCALE));     // round-half-even = jnp.round
  v = fminf(fmaxf(v, -127.f), 127.f);
  return v * QSCALE;
}

// quantize + pack: WQ[(ci*9+tap)*32 + co] = quant(w[co][ci*9+tap])
__global__ __launch_bounds__(256) void quant_k(const float* __restrict__ w1,
                                               const float* __restrict__ w2,
                                               float* __restrict__ q1,
                                               float* __restrict__ q2) {
  int i = blockIdx.x * 256 + threadIdx.x;
  if (i >= 18432) return;
  const float* w = (i < 9216) ? w1 : w2;
  float* dst = (i < 9216) ? q1 : q2;
  int j = (i < 9216) ? i : i - 9216;
  int co = j / 288;
  int r = j - co * 288;                     // r = ci*9 + tap
  dst[r * 32 + co] = quantf(w[j]);
}

// Grid 256 = 32 n x 8 rowgroups(4 rows). Block 1024 thr = 16 waves.
// wave: oct = wv&3 (co oct*8..+7), slice = wv>>2 (ci slice*8..+7).
// lane l: quad = l>>5 (co sub-quad), p = l&31: row = p>>3, g = p&7
// (cols 4g..4g+3). acc[4 cols][4 co] = 16/lane. 16 waves/CU = 4/SIMD.
// Partials ps/pq: chunk-major [256][32], chunk = n*8+rg (coalesced).
template <bool AFFINE>
__global__ __launch_bounds__(1024, 4) void conv_k(
    const float* __restrict__ in,       // [32][32][32][32] conv input
    const float* __restrict__ wq,       // packed [288][32] this conv
    const float* __restrict__ ps_prev,  // [256][32] prev partial sums (or null)
    const float* __restrict__ pq_prev,  // [256][32] prev partial sumsq
    const float* __restrict__ wq_prev,  // packed prev weights (for wb)
    const float* __restrict__ gprev,    // prev gamma
    const float* __restrict__ bprev,    // prev beta
    float* __restrict__ outb,           // raw conv out
    float* __restrict__ ps_out,         // [256][32]
    float* __restrict__ pq_out) {
  // xs = smem[0..6912) : [32 ci][6 rows][36 cols] (idx c <-> global col c-1)
  // wls = smem[6912..16128) : flat [288][32]
  // red aliases smem[0..12288) after compute (SoA [48][256])
  __shared__ __align__(16) float smem[16128];      // 64512 B
  __shared__ float r2a[32][32], r2b[32][32], r2c[32][32];
  __shared__ float abuf[32], bbuf[32];

  float* xs = smem;
  float* wls = smem + 6912;

  const int tid = threadIdx.x;
  const int blk = blockIdx.x;
  const int n = blk >> 3, rg = blk & 7;
  const int h0 = rg << 2;

  if (AFFINE) {
    // Redundant per-block BN1 fold, distributed over all 1024 threads.
    const int c = tid & 31, ch = tid >> 5;    // ch 0..31
    float s = 0.f, q = 0.f;
    #pragma unroll
    for (int k = 0; k < 8; ++k) {
      s += ps_prev[(ch * 8 + k) * 32 + c];
      q += pq_prev[(ch * 8 + k) * 32 + c];
    }
    float wbp = 0.f;
    #pragma unroll
    for (int uu = 0; uu < 9; ++uu)
      wbp += fabsf(wq_prev[(ch * 9 + uu) * 32 + c]);
    r2a[c][ch] = s; r2b[c][ch] = q; r2c[c][ch] = wbp;
    __syncthreads();
    if (tid < 32) {
      double S = 0.0, Q = 0.0; float W = 0.f;
      #pragma unroll 8
      for (int k = 0; k < 32; ++k) {
        S += (double)r2a[tid][k]; Q += (double)r2b[tid][k]; W += r2c[tid][k];
      }
      const double M = 32768.0;
      const double mu = S / M;
      const double var = Q / M - mu * mu;
      const double inv = 1.0 / sqrt(var + 1e-5);
      const double g = (double)gprev[tid];
      abuf[tid] = (float)(g * inv);
      bbuf[tid] = (float)((double)bprev[tid] + (double)(W * (1.f / 288.f)) - g * inv * mu);
    }
    __syncthreads();
  }

  // ---- stage weights (flat float4, coalesced)
  {
    const float4* src = (const float4*)wq;
    float4* dst = (float4*)wls;
    for (int i = tid; i < 2304; i += 1024) dst[i] = src[i];
  }
  // ---- stage x via float4 tasks: 1728 = 32ci x 6rows x 9 slots.
  // slot k<8: f4 load of global cols 4k..4k+3 -> xs idx 4k+1..4k+4;
  // slot k==8: zero the border cells (idx 0 and 33..35).
  for (int i = tid; i < 1728; i += 1024) {
    const int ci = i / 54;
    const int rem = i - ci * 54;
    const int tr = rem / 9, k = rem - tr * 9;
    const int h = h0 - 1 + tr;
    float* dst = xs + ci * 216 + tr * 36;
    if (k < 8) {
      float4 v = {0.f, 0.f, 0.f, 0.f};
      if ((unsigned)h < 32u) {
        v = *(const float4*)(in + (((n * 32 + ci) * 32 + h) * 32 + 4 * k));
        if (AFFINE) {
          const float av = abuf[ci], bv = bbuf[ci];
          v.x = fmaxf(fmaf(av, v.x, bv), 0.f);
          v.y = fmaxf(fmaf(av, v.y, bv), 0.f);
          v.z = fmaxf(fmaf(av, v.z, bv), 0.f);
          v.w = fmaxf(fmaf(av, v.w, bv), 0.f);
        }
      }
      dst[4 * k + 1] = v.x; dst[4 * k + 2] = v.y;
      dst[4 * k + 3] = v.z; dst[4 * k + 4] = v.w;
    } else {
      dst[0] = 0.f; dst[33] = 0.f; dst[34] = 0.f; dst[35] = 0.f;
    }
  }
  __syncthreads();

  const int wv = tid >> 6;
  const int oct = wv & 3, slice = wv >> 2;
  const int l = tid & 63;
  const int quad = l >> 5, p = l & 31;
  const int row = p >> 3, g = p & 7;

  float acc[4][4];
  #pragma unroll
  for (int j = 0; j < 4; ++j)
    #pragma unroll
    for (int k = 0; k < 4; ++k) acc[j][k] = 0.f;

  const float* xpb = xs + row * 36 + 4 * g;
  const float* wpb = wls + oct * 8 + quad * 4;

  #pragma unroll 2
  for (int cc = 0; cc < 8; ++cc) {
    const int ci = slice * 8 + cc;
    const float* xp = xpb + ci * 216;
    float xw[3][6];
    #pragma unroll
    for (int kh = 0; kh < 3; ++kh) {
      const float4 A = *(const float4*)(xp + kh * 36);
      const float2 B = *(const float2*)(xp + kh * 36 + 4);
      xw[kh][0] = A.x; xw[kh][1] = A.y; xw[kh][2] = A.z; xw[kh][3] = A.w;
      xw[kh][4] = B.x; xw[kh][5] = B.y;
    }
    const float* wp = wpb + ci * 288;
    #pragma unroll
    for (int t = 0; t < 9; ++t) {
      const float4 W = *(const float4*)(wp + t * 32);
      const int kh = t / 3, kw = t - kh * 3;
      #pragma unroll
      for (int j = 0; j < 4; ++j) {
        const float xv = xw[kh][j + kw];
        acc[j][0] += fabsf(xv - W.x);
        acc[j][1] += fabsf(xv - W.y);
        acc[j][2] += fabsf(xv - W.z);
        acc[j][3] += fabsf(xv - W.w);
      }
    }
  }
  __syncthreads();   // xs/wls reads done; red may overwrite

  // ---- cross-slice reduce, SoA: red[(s*16 + j*4+k)*256 + oct*64 + l]
  float* red = smem;
  const int lane16 = oct * 64 + l;
  if (slice != 0) {
    const int sb = (slice - 1) * 16;
    #pragma unroll
    for (int j = 0; j < 4; ++j)
      #pragma unroll
      for (int k = 0; k < 4; ++k)
        red[(sb + j * 4 + k) * 256 + lane16] = acc[j][k];
  }
  __syncthreads();

  if (slice == 0) {
    #pragma unroll
    for (int s = 0; s < 3; ++s)
      #pragma unroll
      for (int j = 0; j < 4; ++j)
        #pragma unroll
        for (int k = 0; k < 4; ++k)
          acc[j][k] += red[(s * 16 + j * 4 + k) * 256 + lane16];

    const int h = h0 + row;
    float sv[4], qv[4];
    #pragma unroll
    for (int k = 0; k < 4; ++k) {
      const int co = oct * 8 + quad * 4 + k;
      float4 st;
      st.x = -acc[0][k]; st.y = -acc[1][k]; st.z = -acc[2][k]; st.w = -acc[3][k];
      *(float4*)&outb[((n * 32 + co) * 32 + h) * 32 + 4 * g] = st;
      sv[k] = st.x + st.y + st.z + st.w;
      qv[k] = st.x*st.x + st.y*st.y + st.z*st.z + st.w*st.w;
    }
    #pragma unroll
    for (int d = 1; d < 32; d <<= 1) {
      #pragma unroll
      for (int k = 0; k < 4; ++k) {
        sv[k] += __shfl_xor(sv[k], d);
        qv[k] += __shfl_xor(qv[k], d);
      }
    }
    if (p == 0) {   // lane 0 (quad 0) and lane 32 (quad 1): adjacent float4s
      const int chunk = n * 8 + rg;
      float4 s4; s4.x = sv[0]; s4.y = sv[1]; s4.z = sv[2]; s4.w = sv[3];
      float4 q4; q4.x = qv[0]; q4.y = qv[1]; q4.z = qv[2]; q4.w = qv[3];
      ((float4*)(ps_out + chunk * 32))[oct * 2 + quad] = s4;
      ((float4*)(pq_out + chunk * 32))[oct * 2 + quad] = q4;
    }
  }
}

// ---- K4: redundant BN2 fold + relu(a2*o2 + b2 + x). 512 thr, 512 blocks.
__global__ __launch_bounds__(512) void final_k(
    const float* __restrict__ o2, const float* __restrict__ xres,
    const float* __restrict__ ps, const float* __restrict__ pq,
    const float* __restrict__ wq2, const float* __restrict__ g2,
    const float* __restrict__ b2, float* __restrict__ out) {
  __shared__ float r2a[32][16], r2b[32][16], r2c[32][16];
  __shared__ float abuf[32], bbuf[32];
  const int tid = threadIdx.x;
  const int c = tid & 31, ch = tid >> 5;    // ch 0..15
  float s = 0.f, q = 0.f;
  #pragma unroll
  for (int k = 0; k < 16; ++k) {
    s += ps[(ch * 16 + k) * 32 + c];
    q += pq[(ch * 16 + k) * 32 + c];
  }
  float wbp = 0.f;
  #pragma unroll
  for (int uu = 0; uu < 18; ++uu)
    wbp += fabsf(wq2[(ch * 18 + uu) * 32 + c]);
  r2a[c][ch] = s; r2b[c][ch] = q; r2c[c][ch] = wbp;
  __syncthreads();
  if (tid < 32) {
    double S = 0.0, Q = 0.0; float W = 0.f;
    #pragma unroll
    for (int k = 0; k < 16; ++k) {
      S += (double)r2a[tid][k]; Q += (double)r2b[tid][k]; W += r2c[tid][k];
    }
    const double M = 32768.0;
    const double mu = S / M;
    const double var = Q / M - mu * mu;
    const double inv = 1.0 / sqrt(var + 1e-5);
    const double g = (double)g2[tid];
    abuf[tid] = (float)(g * inv);
    bbuf[tid] = (float)((double)b2[tid] + (double)(W * (1.f / 288.f)) - g * inv * mu);
  }
  __syncthreads();

  const int f4 = blockIdx.x * 512 + tid;   // 512 x 512 = 262144 float4s
  const int cc = (f4 >> 8) & 31;
  const float4 o = ((const float4*)o2)[f4];
  const float4 xr = ((const float4*)xres)[f4];
  const float av = abuf[cc], bvv = bbuf[cc];
  float4 r;
  r.x = fmaxf(fmaf(av, o.x, bvv) + xr.x, 0.f);
  r.y = fmaxf(fmaf(av, o.y, bvv) + xr.y, 0.f);
  r.z = fmaxf(fmaf(av, o.z, bvv) + xr.z, 0.f);
  r.w = fmaxf(fmaf(av, o.w, bvv) + xr.w, 0.f);
  ((float4*)out)[f4] = r;
}

extern "C" void kernel_launch(void* const* d_in, const int* in_sizes, int n_in,
                              void* d_out, int out_size, void* d_ws, size_t ws_size,
                              hipStream_t stream) {
  const float* x   = (const float*)d_in[0];
  const float* w1  = (const float*)d_in[1];
  const float* g1  = (const float*)d_in[2];
  const float* be1 = (const float*)d_in[3];
  const float* w2  = (const float*)d_in[4];
  const float* g2  = (const float*)d_in[5];
  const float* be2 = (const float*)d_in[6];
  float* ws = (float*)d_ws;

  float* WQ1 = ws;                  // 9216  (packed [288][32])
  float* WQ2 = ws + 9216;           // 9216
  float* PS1 = ws + 18432;          // [256][32] = 8192
  float* PQ1 = ws + 26624;          // 8192
  float* PS2 = ws + 34816;          // 8192
  float* PQ2 = ws + 43008;          // 8192
  float* O1  = ws + 51200;          // 1048576 (16B aligned)
  float* O2  = O1 + 1048576;        // 1048576
  float* out = (float*)d_out;

  quant_k<<<72, 256, 0, stream>>>(w1, w2, WQ1, WQ2);
  conv_k<false><<<256, 1024, 0, stream>>>(x, WQ1, nullptr, nullptr, nullptr,
                                          nullptr, nullptr, O1, PS1, PQ1);
  conv_k<true><<<256, 1024, 0, stream>>>(O1, WQ2, PS1, PQ1, WQ1, g1, be1,
                                         O2, PS2, PQ2);
  final_k<<<512, 512, 0, stream>>>(O2, x, PS2, PQ2, WQ2, g2, be2, out);
}